// Round 4
// baseline (278.918 us; speedup 1.0000x reference)
//
#include <hip/hip_runtime.h>

#define F_DIM 225
#define G_DIM 15
#define I_DIM 15
#define H_DIM 5
#define NOUT  75
#define ROWS  16
#define THREADS 256
#define TILE_F4 ((ROWS * F_DIM) / 4)   // 900 float4 = 14400 B per tile

__global__ __launch_bounds__(THREADS) void mlp_main_kernel(
    const float* __restrict__ x,
    const float* __restrict__ w1, const float* __restrict__ b1,
    const float* __restrict__ w2, const float* __restrict__ b2,
    const int* __restrict__ k_idx, const int* __restrict__ v_idx,
    float* __restrict__ out, int ntiles)
{
    __shared__ __align__(16) float x_lds[ROWS * F_DIM];   // 14.4 KB, single buffer

    const int tid = threadIdx.x;
    const int r   = tid / G_DIM;            // local row 0..16
    const int g   = tid - r * G_DIM;        // group 0..14
    const bool active = (tid < ROWS * G_DIM);

    // per-thread index slices, loaded ONCE per persistent block
    int kg[I_DIM];
    int vg[H_DIM];
    if (active) {
#pragma unroll
        for (int i = 0; i < I_DIM; ++i) kg[i] = k_idx[g * I_DIM + i];
#pragma unroll
        for (int o = 0; o < H_DIM; ++o) vg[o] = v_idx[g * H_DIM + o];
    }

    const float4* x4 = reinterpret_cast<const float4*>(x);
    float4* xl4 = reinterpret_cast<float4*>(x_lds);
    const int stride = (int)gridDim.x;

    int t = (int)blockIdx.x;
    if (t >= ntiles) return;

    // prologue: prefetch tile t into registers (plain loads, full-exec safe)
    float4 pf[4];
#pragma unroll
    for (int k = 0; k < 4; ++k) {
        const int idx = tid + k * THREADS;
        if (idx < TILE_F4) pf[k] = x4[(size_t)t * TILE_F4 + idx];
    }

    for (; t < ntiles; t += stride) {
        __syncthreads();   // (A) previous tile's compute finished -> safe to overwrite LDS

        // commit prefetched registers to LDS (compiler inserts the vmcnt drain here)
#pragma unroll
        for (int k = 0; k < 4; ++k) {
            const int idx = tid + k * THREADS;
            if (idx < TILE_F4) xl4[idx] = pf[k];
        }

        __syncthreads();   // (B) tile t visible to all waves

        // issue next tile's loads NOW -> HBM latency hides under compute+store
        const int tn = t + stride;
        if (tn < ntiles) {
#pragma unroll
            for (int k = 0; k < 4; ++k) {
                const int idx = tid + k * THREADS;
                if (idx < TILE_F4) pf[k] = x4[(size_t)tn * TILE_F4 + idx];
            }
        }

        if (active) {
            const float* xr = &x_lds[r * F_DIM];

            float xv[I_DIM];
#pragma unroll
            for (int i = 0; i < I_DIM; ++i) xv[i] = xr[kg[i]];  // stride-15 -> 2 lanes/bank, free

            float hv[H_DIM];
#pragma unroll
            for (int hh = 0; hh < H_DIM; ++hh) {
                float acc = b1[hh];                              // uniform addr -> s_load/K$
#pragma unroll
                for (int i = 0; i < I_DIM; ++i)
                    acc = fmaf(xv[i], w1[hh * I_DIM + i], acc);
                hv[hh] = fmaxf(acc, 0.0f);
            }

            float* orow = out + ((size_t)t * ROWS + r) * NOUT;
#pragma unroll
            for (int oo = 0; oo < H_DIM; ++oo) {
                float acc = b2[oo];
#pragma unroll
                for (int hh = 0; hh < H_DIM; ++hh)
                    acc = fmaf(hv[hh], w2[oo * H_DIM + hh], acc);
                orow[vg[oo]] = acc;                              // direct scatter store
            }
        }
    }
}

// Tail path for B % ROWS != 0 (not hit for B=524288); plain scalar, correctness-first.
__global__ void mlp_tail_kernel(
    const float* __restrict__ x,
    const float* __restrict__ w1, const float* __restrict__ b1,
    const float* __restrict__ w2, const float* __restrict__ b2,
    const int* __restrict__ k_idx, const int* __restrict__ v_idx,
    float* __restrict__ out, int row0, int B)
{
    const int idx = blockIdx.x * blockDim.x + threadIdx.x;
    const int nwork = (B - row0) * G_DIM;
    if (idx >= nwork) return;
    const int r = row0 + idx / G_DIM;
    const int g = idx % G_DIM;

    const float* xr = x + (size_t)r * F_DIM;
    float xv[I_DIM];
#pragma unroll
    for (int i = 0; i < I_DIM; ++i) xv[i] = xr[k_idx[g * I_DIM + i]];

    float hv[H_DIM];
#pragma unroll
    for (int hh = 0; hh < H_DIM; ++hh) {
        float acc = b1[hh];
#pragma unroll
        for (int i = 0; i < I_DIM; ++i) acc = fmaf(xv[i], w1[hh * I_DIM + i], acc);
        hv[hh] = fmaxf(acc, 0.0f);
    }
#pragma unroll
    for (int oo = 0; oo < H_DIM; ++oo) {
        float acc = b2[oo];
#pragma unroll
        for (int hh = 0; hh < H_DIM; ++hh) acc = fmaf(hv[hh], w2[oo * H_DIM + hh], acc);
        out[(size_t)r * NOUT + v_idx[g * H_DIM + oo]] = acc;
    }
}

extern "C" void kernel_launch(void* const* d_in, const int* in_sizes, int n_in,
                              void* d_out, int out_size, void* d_ws, size_t ws_size,
                              hipStream_t stream) {
    const float* x     = (const float*)d_in[0];
    const float* w1    = (const float*)d_in[1];
    const float* b1    = (const float*)d_in[2];
    const float* w2    = (const float*)d_in[3];
    const float* b2    = (const float*)d_in[4];
    const int*   k_idx = (const int*)d_in[5];
    const int*   v_idx = (const int*)d_in[6];
    float* out = (float*)d_out;

    const int B = in_sizes[0] / F_DIM;
    const int ntiles = B / ROWS;

    if (ntiles > 0) {
        const int grid = ntiles < 2048 ? ntiles : 2048;  // persistent, ~16 tiles/block
        mlp_main_kernel<<<grid, THREADS, 0, stream>>>(x, w1, b1, w2, b2,
                                                      k_idx, v_idx, out, ntiles);
    }
    const int row0 = ntiles * ROWS;
    if (row0 < B) {
        const int nwork = (B - row0) * G_DIM;
        const int tgrid = (nwork + THREADS - 1) / THREADS;
        mlp_tail_kernel<<<tgrid, THREADS, 0, stream>>>(x, w1, b1, w2, b2,
                                                       k_idx, v_idx, out, row0, B);
    }
}

// Round 5
// 119.778 us; speedup vs baseline: 2.3286x; 2.3286x over previous
//
#include <hip/hip_runtime.h>

#define F_DIM 225
#define G_DIM 15
#define I_DIM 15
#define H_DIM 5
#define NOUT  75
#define ROWS  16
#define THREADS 256
#define TILE_F4 ((ROWS * F_DIM) / 4)   // 900 float4 = 14400 B per tile
#define OUT_F4  ((ROWS * NOUT) / 4)    // 300 float4 = 4800 B per tile

__global__ __launch_bounds__(THREADS) void mlp_rsna_kernel(
    const float* __restrict__ x,
    const float* __restrict__ w1, const float* __restrict__ b1,
    const float* __restrict__ w2, const float* __restrict__ b2,
    const int* __restrict__ k_idx, const int* __restrict__ v_idx,
    float* __restrict__ out, int B)
{
    // LDS: 14.4 KB x-tile + 4.8 KB out-tile + idx tables ~= 20.5 KB -> 7 blocks/CU
    __shared__ __align__(16) float x_lds[ROWS * F_DIM];   // 3600 f32
    __shared__ __align__(16) float o_lds[ROWS * NOUT];    // 1200 f32
    __shared__ int k_lds[G_DIM * I_DIM];                  // 225
    __shared__ int v_lds[G_DIM * H_DIM];                  // 75

    const int tid = threadIdx.x;
    const int block_row0 = (int)blockIdx.x * ROWS;
    const int rows_here = min(ROWS, B - block_row0);

    // ---- stage idx tables (tiny, L2-hit) ----
    if (tid < G_DIM * I_DIM) k_lds[tid] = k_idx[tid];
    if (tid < G_DIM * H_DIM) v_lds[tid] = v_idx[tid];

    // ---- stage x rows: coalesced float4 -> LDS (R3-proven path) ----
    if (rows_here == ROWS) {
        const float4* src4 = reinterpret_cast<const float4*>(x + (size_t)block_row0 * F_DIM);
        float4* xl4 = reinterpret_cast<float4*>(x_lds);
#pragma unroll
        for (int k = 0; k < 4; ++k) {
            int idx = tid + k * THREADS;
            if (idx < TILE_F4) xl4[idx] = src4[idx];
        }
    } else {
        const float* src = x + (size_t)block_row0 * F_DIM;
        for (int k = tid; k < rows_here * F_DIM; k += THREADS) x_lds[k] = src[k];
    }

    // ---- zero out-tile (reference semantics: zeros + scatter) ----
    for (int k = tid; k < ROWS * NOUT; k += THREADS) o_lds[k] = 0.0f;

    __syncthreads();

    // ---- compute: one thread per (row, group); weights via uniform/scalar loads ----
    if (tid < rows_here * G_DIM) {
        const int r = tid / G_DIM;
        const int g = tid - r * G_DIM;
        const float* xr = &x_lds[r * F_DIM];

        float xv[I_DIM];
#pragma unroll
        for (int i = 0; i < I_DIM; ++i) xv[i] = xr[k_lds[g * I_DIM + i]];

        float hv[H_DIM];
#pragma unroll
        for (int hh = 0; hh < H_DIM; ++hh) {
            float acc = b1[hh];                              // uniform addr -> s_load/K$
#pragma unroll
            for (int i = 0; i < I_DIM; ++i)
                acc = fmaf(xv[i], w1[hh * I_DIM + i], acc);
            hv[hh] = fmaxf(acc, 0.0f);
        }

        float* orow = &o_lds[r * NOUT];
#pragma unroll
        for (int oo = 0; oo < H_DIM; ++oo) {
            float acc = b2[oo];
#pragma unroll
            for (int hh = 0; hh < H_DIM; ++hh)
                acc = fmaf(hv[hh], w2[oo * H_DIM + hh], acc);
            orow[v_lds[g * H_DIM + oo]] = acc;               // LDS scatter (cheap)
        }
    }

    __syncthreads();

    // ---- dense float4 writeback: 75 fully-written aligned 64B lines per block ----
    if (rows_here == ROWS) {
        float4* dst4 = reinterpret_cast<float4*>(out + (size_t)block_row0 * NOUT);
        const float4* ol4 = reinterpret_cast<const float4*>(o_lds);
        for (int k = tid; k < OUT_F4; k += THREADS) dst4[k] = ol4[k];
    } else {
        float* dst = out + (size_t)block_row0 * NOUT;
        for (int k = tid; k < rows_here * NOUT; k += THREADS) dst[k] = o_lds[k];
    }
}

extern "C" void kernel_launch(void* const* d_in, const int* in_sizes, int n_in,
                              void* d_out, int out_size, void* d_ws, size_t ws_size,
                              hipStream_t stream) {
    const float* x     = (const float*)d_in[0];
    const float* w1    = (const float*)d_in[1];
    const float* b1    = (const float*)d_in[2];
    const float* w2    = (const float*)d_in[3];
    const float* b2    = (const float*)d_in[4];
    const int*   k_idx = (const int*)d_in[5];
    const int*   v_idx = (const int*)d_in[6];
    float* out = (float*)d_out;

    const int B = in_sizes[0] / F_DIM;
    const int grid = (B + ROWS - 1) / ROWS;
    mlp_rsna_kernel<<<grid, THREADS, 0, stream>>>(x, w1, b1, w2, b2, k_idx, v_idx, out, B);
}

// Round 7
// 106.547 us; speedup vs baseline: 2.6178x; 1.1242x over previous
//
#include <hip/hip_runtime.h>

#define F_DIM 225
#define G_DIM 15
#define I_DIM 15
#define H_DIM 5
#define NOUT  75
#define ROWS  32
#define THREADS 512
#define TILE_F4 ((ROWS * F_DIM) / 4)   // 1800 float4 = 28800 B per tile
#define OUT_F4  ((ROWS * NOUT) / 4)    // 600 float4  = 9600 B per tile

typedef float vfloat4 __attribute__((ext_vector_type(4)));  // native vec for nontemporal builtins

__global__ __launch_bounds__(THREADS) void mlp_rsna_kernel(
    const float* __restrict__ x,
    const float* __restrict__ w1, const float* __restrict__ b1,
    const float* __restrict__ w2, const float* __restrict__ b2,
    const int* __restrict__ k_idx, const int* __restrict__ v_idx,
    float* __restrict__ out, int B)
{
    // LDS: 28.8 KB x-tile + 9.6 KB out-tile + idx tables ~= 39.6 KB
    // -> 4 blocks/CU x 8 waves = 32 waves/CU (max occupancy)
    __shared__ __align__(16) float x_lds[ROWS * F_DIM];   // 7200 f32
    __shared__ __align__(16) float o_lds[ROWS * NOUT];    // 2400 f32
    __shared__ int k_lds[G_DIM * I_DIM];                  // 225
    __shared__ int v_lds[G_DIM * H_DIM];                  // 75

    const int tid = threadIdx.x;
    const int block_row0 = (int)blockIdx.x * ROWS;
    const int rows_here = min(ROWS, B - block_row0);

    // ---- stage idx tables (tiny, L2-hit) ----
    if (tid < G_DIM * I_DIM) k_lds[tid] = k_idx[tid];
    if (tid < G_DIM * H_DIM) v_lds[tid] = v_idx[tid];

    // ---- stage x rows: coalesced nontemporal float4 -> LDS ----
    if (rows_here == ROWS) {
        const vfloat4* src4 = reinterpret_cast<const vfloat4*>(x + (size_t)block_row0 * F_DIM);
        vfloat4* xl4 = reinterpret_cast<vfloat4*>(x_lds);
#pragma unroll
        for (int k = 0; k < 4; ++k) {
            int idx = tid + k * THREADS;
            if (idx < TILE_F4) xl4[idx] = __builtin_nontemporal_load(src4 + idx);
        }
    } else {
        const float* src = x + (size_t)block_row0 * F_DIM;
        for (int k = tid; k < rows_here * F_DIM; k += THREADS) x_lds[k] = src[k];
    }

    // ---- zero out-tile (reference semantics: zeros + scatter) ----
    for (int k = tid; k < ROWS * NOUT; k += THREADS) o_lds[k] = 0.0f;

    __syncthreads();

    // ---- compute: one thread per (row, group); weights via uniform/scalar loads ----
    if (tid < rows_here * G_DIM) {
        const int r = tid / G_DIM;
        const int g = tid - r * G_DIM;
        const float* xr = &x_lds[r * F_DIM];

        float xv[I_DIM];
#pragma unroll
        for (int i = 0; i < I_DIM; ++i) xv[i] = xr[k_lds[g * I_DIM + i]];

        float hv[H_DIM];
#pragma unroll
        for (int hh = 0; hh < H_DIM; ++hh) {
            float acc = b1[hh];                              // uniform addr -> s_load/K$
#pragma unroll
            for (int i = 0; i < I_DIM; ++i)
                acc = fmaf(xv[i], w1[hh * I_DIM + i], acc);
            hv[hh] = fmaxf(acc, 0.0f);
        }

        float* orow = &o_lds[r * NOUT];
#pragma unroll
        for (int oo = 0; oo < H_DIM; ++oo) {
            float acc = b2[oo];
#pragma unroll
            for (int hh = 0; hh < H_DIM; ++hh)
                acc = fmaf(hv[hh], w2[oo * H_DIM + hh], acc);
            orow[v_lds[g * H_DIM + oo]] = acc;               // LDS scatter (cheap)
        }
    }

    __syncthreads();

    // ---- dense nontemporal float4 writeback: fully-written aligned 64B lines ----
    if (rows_here == ROWS) {
        vfloat4* dst4 = reinterpret_cast<vfloat4*>(out + (size_t)block_row0 * NOUT);
        const vfloat4* ol4 = reinterpret_cast<const vfloat4*>(o_lds);
#pragma unroll
        for (int k = 0; k < 2; ++k) {
            int idx = tid + k * THREADS;
            if (idx < OUT_F4) __builtin_nontemporal_store(ol4[idx], dst4 + idx);
        }
    } else {
        float* dst = out + (size_t)block_row0 * NOUT;
        for (int k = tid; k < rows_here * NOUT; k += THREADS) dst[k] = o_lds[k];
    }
}

extern "C" void kernel_launch(void* const* d_in, const int* in_sizes, int n_in,
                              void* d_out, int out_size, void* d_ws, size_t ws_size,
                              hipStream_t stream) {
    const float* x     = (const float*)d_in[0];
    const float* w1    = (const float*)d_in[1];
    const float* b1    = (const float*)d_in[2];
    const float* w2    = (const float*)d_in[3];
    const float* b2    = (const float*)d_in[4];
    const int*   k_idx = (const int*)d_in[5];
    const int*   v_idx = (const int*)d_in[6];
    float* out = (float*)d_out;

    const int B = in_sizes[0] / F_DIM;
    const int grid = (B + ROWS - 1) / ROWS;
    mlp_rsna_kernel<<<grid, THREADS, 0, stream>>>(x, w1, b1, w2, b2, k_idx, v_idx, out, B);
}